// Round 1
// baseline (2383.019 us; speedup 1.0000x reference)
//
#include <hip/hip_runtime.h>
#include <math.h>

// Problem constants (from reference): B=4, H=16, L=S=2048, D=64, fp32.
constexpr int Bc = 4, Hc = 16, Lc = 2048, Sc = 2048, Dc = 64;
constexpr float SCALE = 0.125f;  // 1/sqrt(64)

constexpr int BM = 64;    // Q rows per block
constexpr int CK = 64;    // S-chunk per iteration
constexpr int NT = 256;   // threads per block (4 waves)
constexpr int LDSP = 65;  // padded LDS row stride (floats) -> conflict-free b32

// Fused attention:
//  pass 1: logits = scale * Q K^T  -> written raw into scores buffer,
//          online row max m and denom l kept in registers.
//  pass 2: read logits back, p = exp(x - m)/l, overwrite scores with p,
//          accumulate O = P V via LDS-staged P and V^T.
__global__ __launch_bounds__(NT, 4) void attn_fused(
    const float* __restrict__ q, const float* __restrict__ k,
    const float* __restrict__ v, float* __restrict__ out,
    float* __restrict__ scores) {
  // smA: pass1 = Q tile [BM][LDSP]; pass2 = P tile [BM][LDSP]
  // smB: pass1 = K chunk [CK][LDSP]; pass2 = V^T chunk [Dc][LDSP]
  __shared__ float smA[BM * LDSP];
  __shared__ float smB[CK * LDSP];

  const int bh = blockIdx.y;       // 0..B*H-1
  const int l0 = blockIdx.x * BM;  // q-row tile start
  const int tid = threadIdx.x;

  const float* qp = q + (size_t)bh * Lc * Dc + (size_t)l0 * Dc;
  const float* kp = k + (size_t)bh * Sc * Dc;
  const float* vp = v + (size_t)bh * Sc * Dc;
  float* sc = scores + (size_t)bh * Lc * Sc + (size_t)l0 * Sc;
  float* op = out + (size_t)bh * Lc * Dc + (size_t)l0 * Dc;

  const int ty = tid >> 4;  // 0..15 -> rows 4*ty..4*ty+3
  const int tx = tid & 15;  // 0..15 -> cols 4*tx..4*tx+3
  const int r0 = ty * 4;
  const int c0 = tx * 4;

  // ---- stage Q tile (64x64 floats = 1024 float4) ----
#pragma unroll
  for (int i = 0; i < 4; ++i) {
    int f = tid + NT * i;  // 0..1023
    int r = f >> 4;        // 0..63
    int c4 = f & 15;       // float4 column
    float4 val = reinterpret_cast<const float4*>(qp + (size_t)r * Dc)[c4];
    float* dst = &smA[r * LDSP + c4 * 4];
    dst[0] = val.x; dst[1] = val.y; dst[2] = val.z; dst[3] = val.w;
  }

  float mrow[4], lrow[4];
#pragma unroll
  for (int i = 0; i < 4; ++i) {
    mrow[i] = -INFINITY;
    lrow[i] = 0.0f;
  }

  __syncthreads();  // Q tile ready

  // =================== PASS 1: logits + online stats ===================
  for (int s0 = 0; s0 < Sc; s0 += CK) {
    // stage K chunk (64x64)
#pragma unroll
    for (int i = 0; i < 4; ++i) {
      int f = tid + NT * i;
      int r = f >> 4;
      int c4 = f & 15;
      float4 val =
          reinterpret_cast<const float4*>(kp + (size_t)(s0 + r) * Dc)[c4];
      float* dst = &smB[r * LDSP + c4 * 4];
      dst[0] = val.x; dst[1] = val.y; dst[2] = val.z; dst[3] = val.w;
    }
    __syncthreads();  // K ready

    float acc[4][4];
#pragma unroll
    for (int i = 0; i < 4; ++i)
#pragma unroll
      for (int j = 0; j < 4; ++j) acc[i][j] = 0.0f;

#pragma unroll 8
    for (int d = 0; d < Dc; ++d) {
      float qv[4], kv[4];
#pragma unroll
      for (int i = 0; i < 4; ++i) qv[i] = smA[(r0 + i) * LDSP + d];
#pragma unroll
      for (int j = 0; j < 4; ++j) kv[j] = smB[(c0 + j) * LDSP + d];
#pragma unroll
      for (int i = 0; i < 4; ++i)
#pragma unroll
        for (int j = 0; j < 4; ++j) acc[i][j] += qv[i] * kv[j];
    }

    // scale, write raw logits, update online stats
#pragma unroll
    for (int i = 0; i < 4; ++i) {
#pragma unroll
      for (int j = 0; j < 4; ++j) acc[i][j] *= SCALE;

      float4 st = {acc[i][0], acc[i][1], acc[i][2], acc[i][3]};
      reinterpret_cast<float4*>(sc + (size_t)(r0 + i) * Sc + s0)[tx] = st;

      float cm = fmaxf(fmaxf(acc[i][0], acc[i][1]), fmaxf(acc[i][2], acc[i][3]));
#pragma unroll
      for (int off = 1; off < 16; off <<= 1) cm = fmaxf(cm, __shfl_xor(cm, off));
      float mnew = fmaxf(mrow[i], cm);
      float ps = __expf(acc[i][0] - mnew) + __expf(acc[i][1] - mnew) +
                 __expf(acc[i][2] - mnew) + __expf(acc[i][3] - mnew);
#pragma unroll
      for (int off = 1; off < 16; off <<= 1) ps += __shfl_xor(ps, off);
      lrow[i] = lrow[i] * __expf(mrow[i] - mnew) + ps;
      mrow[i] = mnew;
    }
    __syncthreads();  // everyone done reading K (and Q still live in smA)
  }

  float invl[4];
#pragma unroll
  for (int i = 0; i < 4; ++i) invl[i] = 1.0f / lrow[i];

  // =================== PASS 2: probs + P V ===================
  float oacc[4][4];
#pragma unroll
  for (int i = 0; i < 4; ++i)
#pragma unroll
    for (int j = 0; j < 4; ++j) oacc[i][j] = 0.0f;

  for (int s0 = 0; s0 < Sc; s0 += CK) {
    // stage V chunk transposed: smB[d][s] = V[s0+s][d]
#pragma unroll
    for (int i = 0; i < 4; ++i) {
      int f = tid + NT * i;
      int r = f >> 4;   // s within chunk
      int c4 = f & 15;  // float4 column along d
      float4 val =
          reinterpret_cast<const float4*>(vp + (size_t)(s0 + r) * Dc)[c4];
      smB[(4 * c4 + 0) * LDSP + r] = val.x;
      smB[(4 * c4 + 1) * LDSP + r] = val.y;
      smB[(4 * c4 + 2) * LDSP + r] = val.z;
      smB[(4 * c4 + 3) * LDSP + r] = val.w;
    }

    // read logits back (same thread wrote them), make probs, stage P
#pragma unroll
    for (int i = 0; i < 4; ++i) {
      float4 lg =
          reinterpret_cast<const float4*>(sc + (size_t)(r0 + i) * Sc + s0)[tx];
      float4 pr;
      pr.x = __expf(lg.x - mrow[i]) * invl[i];
      pr.y = __expf(lg.y - mrow[i]) * invl[i];
      pr.z = __expf(lg.z - mrow[i]) * invl[i];
      pr.w = __expf(lg.w - mrow[i]) * invl[i];
      reinterpret_cast<float4*>(sc + (size_t)(r0 + i) * Sc + s0)[tx] = pr;
      float* dst = &smA[(r0 + i) * LDSP + c0];
      dst[0] = pr.x; dst[1] = pr.y; dst[2] = pr.z; dst[3] = pr.w;
    }
    __syncthreads();  // P and V^T ready

    // O += P[64 x 64] * V[64 x 64]; micro-tile 4 rows x 4 d-cols
#pragma unroll 8
    for (int s = 0; s < CK; ++s) {
      float pv[4], vv[4];
#pragma unroll
      for (int i = 0; i < 4; ++i) pv[i] = smA[(r0 + i) * LDSP + s];
#pragma unroll
      for (int j = 0; j < 4; ++j) vv[j] = smB[(c0 + j) * LDSP + s];
#pragma unroll
      for (int i = 0; i < 4; ++i)
#pragma unroll
        for (int j = 0; j < 4; ++j) oacc[i][j] += pv[i] * vv[j];
    }
    __syncthreads();  // done reading P/V^T before next chunk restages
  }

  // write attention output
#pragma unroll
  for (int i = 0; i < 4; ++i) {
    float4 o = {oacc[i][0], oacc[i][1], oacc[i][2], oacc[i][3]};
    reinterpret_cast<float4*>(op + (size_t)(r0 + i) * Dc)[tx] = o;
  }
}

extern "C" void kernel_launch(void* const* d_in, const int* in_sizes, int n_in,
                              void* d_out, int out_size, void* d_ws,
                              size_t ws_size, hipStream_t stream) {
  const float* q = (const float*)d_in[0];
  const float* k = (const float*)d_in[1];
  const float* v = (const float*)d_in[2];
  float* out = (float*)d_out;
  float* scores = out + (size_t)Bc * Hc * Lc * Dc;  // tuple: (output, scores)

  dim3 grid(Lc / BM, Bc * Hc);
  attn_fused<<<grid, NT, 0, stream>>>(q, k, v, out, scores);
}